// Round 8
// baseline (31.447 us; speedup 1.0000x reference)
//
#include <hip/hip_runtime.h>
#include <cmath>

// VarRateResampler ratio=2: per (b,t) two 21-tap FIRs, polyphase rows chosen
// by an NCO with step s = 64 + acc_phase. Closed form for the NCO state
// entering step t:  a_t = ceil(t*Q/s)*s - t*Q  (invariant a in [0,Q)).
// Round 8 = round 7 with ONE change: TPT 4 -> 8 (halves L1 load traffic and
// instruction issue; threads 2M -> 1M). Round 4's TPT=8 failure was NT-store
// line eviction (WRITE 118MB); round 7 proved regular stores write exactly
// 65.5MB, so TPT=8 + regular stores should not amplify.
//  - x window: 28 floats via 7 aligned float4 loads, no LDS, no barrier
//  - NCO: exact a==0 shortcut for step==64, f64 closed form otherwise
//  - taps via wave-uniform scalar loads (s_load, once per wave)
//  - stores: 4 REGULAR float4 per thread (64B lane-stride, L2 merges)

#define QQ   128
#define LT   21
#define TT   4096
#define TPT  8                 // t per thread
#define BLK  256
#define TILE (BLK * TPT)       // 2048 t per block

__global__ __launch_bounds__(BLK) void fir_kernel(
    const float* __restrict__ x,
    const float* __restrict__ hs,
    const float* __restrict__ accp,
    float*       __restrict__ y)
{
    const int b  = blockIdx.y;
    const int t0 = blockIdx.x * TILE + threadIdx.x * TPT;
    const size_t row = (size_t)b * TT;

    // ---- x window x[t0-20 .. t0+7] : 28 floats, base (8m-20) 16B-aligned ----
    float xr[28];
    const int base = t0 - 20;
    if (base >= 0) {
        const float4* src = (const float4*)(x + row + base);
        #pragma unroll
        for (int q = 0; q < 7; ++q) {
            float4 v = src[q];
            xr[4*q+0] = v.x; xr[4*q+1] = v.y; xr[4*q+2] = v.z; xr[4*q+3] = v.w;
        }
    } else {                      // only threads 0..2 of each row's first block
        #pragma unroll
        for (int i = 0; i < 28; ++i) {
            int gt = base + i;
            xr[i] = (gt >= 0) ? x[row + gt] : 0.0f;   // fifo zero-init
        }
    }

    // ---- NCO seed: exact shortcut for s==64, f64 closed form otherwise ----
    const float sf = 64.0f + accp[0];                 // step_inc (f32)
    float a;
    if (sf == 64.0f) {
        a = 0.0f;            // ceil(2t)=2t exactly => a_t = 0 for every t
    } else {
        const double s = (double)sf;
        const double tq0 = (double)t0 * 128.0;
        a = (float)(__builtin_ceil(tq0 / s) * s - tq0);   // acc entering t0
    }

    // ---- exact reference f32 recurrence over the 8 slots ----
    int i0[TPT], i1[TPT];
    #pragma unroll
    for (int k = 0; k < TPT; ++k) {
        bool  v0   = a < 128.0f;                      // slot 0
        float ind0 = v0 ? a : -1.0f;
        float ap   = v0 ? a + sf : a;
        bool  v1   = ap < 128.0f;                     // slot 1
        float ind1 = v1 ? ap : -1.0f;
        float an   = v1 ? ap + sf : ap;
        a = an - 128.0f;                              // wrap
        i0[k] = min((int)rintf(ind0), QQ - 1);        // -1 => NaN row
        i1[k] = min((int)rintf(ind1), QQ - 1);
    }

    // ---- wave-uniform fast path check ----
    bool uni = true;
    #pragma unroll
    for (int k = 1; k < TPT; ++k) uni &= (i0[k] == i0[0]) & (i1[k] == i1[0]);
    const int f0 = __builtin_amdgcn_readfirstlane(i0[0]);
    const int f1 = __builtin_amdgcn_readfirstlane(i1[0]);
    uni &= (i0[0] == f0) & (i1[0] == f1);

    float out[2 * TPT];

    if (__all(uni) && f0 >= 0 && f1 >= 0) {
        // taps are wave-uniform -> scalar loads into SGPRs, once per wave
        const float* __restrict__ h0 = hs + (size_t)f0 * LT;
        const float* __restrict__ h1 = hs + (size_t)f1 * LT;
        #pragma unroll
        for (int k = 0; k < TPT; ++k) {
            float a0 = 0.0f, a1 = 0.0f;
            #pragma unroll
            for (int l = 0; l < LT; ++l) {
                a0 = fmaf(h0[l], xr[k + l], a0);
                a1 = fmaf(h1[l], xr[k + l], a1);
            }
            out[2*k]     = a0;
            out[2*k + 1] = a1;
        }
    } else {
        // generic per-lane gather path (any acc_phase); correctness-only
        const float NaNf = __int_as_float(0x7fc00000);
        #pragma unroll
        for (int k = 0; k < TPT; ++k) {
            const int r0 = i0[k], r1 = i1[k];
            float a0 = 0.0f, a1 = 0.0f;
            if (r0 >= 0) {
                const float* hp = hs + (size_t)r0 * LT;
                #pragma unroll
                for (int l = 0; l < LT; ++l) a0 = fmaf(hp[l], xr[k + l], a0);
            } else a0 = NaNf;
            if (r1 >= 0) {
                const float* hp = hs + (size_t)r1 * LT;
                #pragma unroll
                for (int l = 0; l < LT; ++l) a1 = fmaf(hp[l], xr[k + l], a1);
            } else a1 = NaNf;
            out[2*k]     = a0;
            out[2*k + 1] = a1;
        }
    }

    // ---- write (B, T, 2): 16 floats = 4 REGULAR float4 stores ----
    float4* yq = (float4*)(y + (row + (size_t)t0) * 2);
    #pragma unroll
    for (int q = 0; q < 4; ++q)
        yq[q] = make_float4(out[4*q+0], out[4*q+1], out[4*q+2], out[4*q+3]);
}

extern "C" void kernel_launch(void* const* d_in, const int* in_sizes, int n_in,
                              void* d_out, int out_size, void* d_ws, size_t ws_size,
                              hipStream_t stream) {
    const float* x    = (const float*)d_in[0];   // (B, 4096) f32
    const float* hs   = (const float*)d_in[1];   // (128, 21) f32
    const float* accp = (const float*)d_in[2];   // scalar f32
    float* y = (float*)d_out;                    // (B, 4096, 2) f32

    const int B = in_sizes[0] / TT;

    dim3 grid(TT / TILE, B);                     // (2, 2048)
    fir_kernel<<<grid, BLK, 0, stream>>>(x, hs, accp, y);
}

// Round 9
// 25.354 us; speedup vs baseline: 1.2403x; 1.2403x over previous
//
#include <hip/hip_runtime.h>
#include <cmath>

// VarRateResampler ratio=2: per (b,t) two 21-tap FIRs, polyphase rows chosen
// by an NCO with step s = 64 + acc_phase.
// Round 9: software-pipelined persistent-row kernel. One block per row
// (grid=2048 = 8 blocks/CU, all co-resident); each thread produces 4 tiles
// (TPT=4 t each, spaced 1024 apart). Program order interleaves
//   loadA, loadB, fir+storeA, loadA', fir+storeB, loadB', ...
// so tile j+1's 6 loads are in flight during tile j's FIR -> hides the
// ~600-900cy load latency INSIDE each wave (r8 evidence: 20% VALUBusy,
// waves parked on vmcnt; traffic already minimal 16.5+65.5 MB).
// step==64.0 (benchmark case): NCO indices are provably (0,64) for every t
// (a_t == 0 exactly), so the fast pipeline has zero per-tile NCO cost.
// Generic acc_phase path kept as a non-unrolled correctness loop.
// Loads: 6 aligned float4 (r5/r7-proven); stores: 2 regular float4 @32B
// lane-stride (r7-proven exact 65.5 MB).

#define QQ    128
#define LT    21
#define TT    4096
#define TPT   4
#define BLK   256
#define SPAN  (BLK * TPT)      // 1024 t per tile
#define NTILE (TT / SPAN)      // 4 tiles per row

__global__ __launch_bounds__(BLK) void fir_kernel(
    const float* __restrict__ x,
    const float* __restrict__ hs,
    const float* __restrict__ accp,
    float*       __restrict__ y)
{
    const int   tid = threadIdx.x;
    const size_t row = (size_t)blockIdx.x * TT;
    const float sf = 64.0f + accp[0];                 // step_inc (f32)

    // ---- tile loaders: 24-float window, 16B-aligned float4 x6 ----
    auto load_tile = [&](float (&xr)[24], int j) {
        const int base = j * SPAN + tid * TPT - 20;   // (4m-20)%4==0, base>=0
        const float4* src = (const float4*)(x + row + base);
        #pragma unroll
        for (int q = 0; q < 6; ++q) {
            float4 v = src[q];
            xr[4*q+0] = v.x; xr[4*q+1] = v.y; xr[4*q+2] = v.z; xr[4*q+3] = v.w;
        }
    };
    auto load_tile0 = [&](float (&xr)[24]) {          // j==0: fifo zero-fill
        const int base = tid * TPT - 20;
        if (base >= 0) {
            const float4* src = (const float4*)(x + row + base);
            #pragma unroll
            for (int q = 0; q < 6; ++q) {
                float4 v = src[q];
                xr[4*q+0] = v.x; xr[4*q+1] = v.y; xr[4*q+2] = v.z; xr[4*q+3] = v.w;
            }
        } else {                                      // threads 0..4 only
            #pragma unroll
            for (int i = 0; i < 24; ++i) {
                int gt = base + i;
                xr[i] = (gt >= 0) ? x[row + gt] : 0.0f;
            }
        }
    };

    // ---- FIR on one tile with wave-uniform taps, then store ----
    auto fir_store = [&](const float (&xr)[24], const float* __restrict__ h0,
                         const float* __restrict__ h1, int j) {
        float out[8];
        #pragma unroll
        for (int k = 0; k < TPT; ++k) {
            float a0 = 0.0f, a1 = 0.0f;
            #pragma unroll
            for (int l = 0; l < LT; ++l) {
                a0 = fmaf(h0[l], xr[k + l], a0);
                a1 = fmaf(h1[l], xr[k + l], a1);
            }
            out[2*k] = a0; out[2*k+1] = a1;
        }
        const int t0 = j * SPAN + tid * TPT;
        float4* yq = (float4*)(y + (row + (size_t)t0) * 2);
        yq[0] = make_float4(out[0], out[1], out[2], out[3]);
        yq[1] = make_float4(out[4], out[5], out[6], out[7]);
    };

    if (sf == 64.0f) {
        // a_t == 0 exactly for all t => rows (0, 64) always; taps pointers
        // are compile-time-uniform -> s_load into SGPRs once per wave.
        const float* __restrict__ h0 = hs;                    // row 0
        const float* __restrict__ h1 = hs + 64 * LT;          // row 64
        float xrA[24], xrB[24];
        load_tile0(xrA);                 // tile 0 loads in flight
        load_tile (xrB, 1);              // tile 1 loads in flight
        fir_store(xrA, h0, h1, 0);       // compute 0 under tile-1 latency
        load_tile (xrA, 2);              // tile 2 loads in flight
        fir_store(xrB, h0, h1, 1);       // compute 1 under tile-2 latency
        load_tile (xrB, 3);              // tile 3 loads in flight
        fir_store(xrA, h0, h1, 2);
        fir_store(xrB, h0, h1, 3);
        return;
    }

    // ---- generic acc_phase path (correctness-only, not pipelined) ----
    const double s = (double)sf;
    #pragma unroll 1
    for (int j = 0; j < NTILE; ++j) {
        const int t0 = j * SPAN + tid * TPT;

        float xr[24];
        if (j == 0) load_tile0(xr); else load_tile(xr, j);

        // f64 closed-form seed + exact reference f32 recurrence
        const double tq0 = (double)t0 * 128.0;
        float a = (float)(__builtin_ceil(tq0 / s) * s - tq0);
        int i0[TPT], i1[TPT];
        #pragma unroll
        for (int k = 0; k < TPT; ++k) {
            bool  v0   = a < 128.0f;
            float ind0 = v0 ? a : -1.0f;
            float ap   = v0 ? a + sf : a;
            bool  v1   = ap < 128.0f;
            float ind1 = v1 ? ap : -1.0f;
            float an   = v1 ? ap + sf : ap;
            a = an - 128.0f;
            i0[k] = min((int)rintf(ind0), QQ - 1);
            i1[k] = min((int)rintf(ind1), QQ - 1);
        }

        bool uni = true;
        #pragma unroll
        for (int k = 1; k < TPT; ++k) uni &= (i0[k] == i0[0]) & (i1[k] == i1[0]);
        const int f0 = __builtin_amdgcn_readfirstlane(i0[0]);
        const int f1 = __builtin_amdgcn_readfirstlane(i1[0]);
        uni &= (i0[0] == f0) & (i1[0] == f1);

        float out[8];
        if (__all(uni) && f0 >= 0 && f1 >= 0) {
            const float* __restrict__ h0 = hs + (size_t)f0 * LT;
            const float* __restrict__ h1 = hs + (size_t)f1 * LT;
            #pragma unroll
            for (int k = 0; k < TPT; ++k) {
                float a0 = 0.0f, a1 = 0.0f;
                #pragma unroll
                for (int l = 0; l < LT; ++l) {
                    a0 = fmaf(h0[l], xr[k + l], a0);
                    a1 = fmaf(h1[l], xr[k + l], a1);
                }
                out[2*k] = a0; out[2*k+1] = a1;
            }
        } else {
            const float NaNf = __int_as_float(0x7fc00000);
            #pragma unroll
            for (int k = 0; k < TPT; ++k) {
                const int r0 = i0[k], r1 = i1[k];
                float a0 = 0.0f, a1 = 0.0f;
                if (r0 >= 0) {
                    const float* hp = hs + (size_t)r0 * LT;
                    #pragma unroll
                    for (int l = 0; l < LT; ++l) a0 = fmaf(hp[l], xr[k + l], a0);
                } else a0 = NaNf;
                if (r1 >= 0) {
                    const float* hp = hs + (size_t)r1 * LT;
                    #pragma unroll
                    for (int l = 0; l < LT; ++l) a1 = fmaf(hp[l], xr[k + l], a1);
                } else a1 = NaNf;
                out[2*k] = a0; out[2*k+1] = a1;
            }
        }

        float4* yq = (float4*)(y + (row + (size_t)t0) * 2);
        yq[0] = make_float4(out[0], out[1], out[2], out[3]);
        yq[1] = make_float4(out[4], out[5], out[6], out[7]);
    }
}

extern "C" void kernel_launch(void* const* d_in, const int* in_sizes, int n_in,
                              void* d_out, int out_size, void* d_ws, size_t ws_size,
                              hipStream_t stream) {
    const float* x    = (const float*)d_in[0];   // (B, 4096) f32
    const float* hs   = (const float*)d_in[1];   // (128, 21) f32
    const float* accp = (const float*)d_in[2];   // scalar f32
    float* y = (float*)d_out;                    // (B, 4096, 2) f32

    const int B = in_sizes[0] / TT;              // 2048 rows

    fir_kernel<<<dim3(B), BLK, 0, stream>>>(x, hs, accp, y);
}

// Round 10
// 24.484 us; speedup vs baseline: 1.2844x; 1.0355x over previous
//
#include <hip/hip_runtime.h>
#include <cmath>

// VarRateResampler ratio=2: per (b,t) two 21-tap FIRs, polyphase rows chosen
// by an NCO with step s = 64 + acc_phase (a_t = ceil(t*Q/s)*s - t*Q).
// Round 10: one block per ROW, whole row staged to LDS once.
//   - stage: 4 aligned float4 loads/thread + ds_write_b128 (conflict-free),
//     20-float FIFO head zero-filled in LDS (no halo loads, no misalignment)
//   - split staging in halves; second half's global loads issue before
//     compute-A so ~1300cy of FMA hides their latency; ONE read-wait per
//     block instead of one per 4 outputs (r5..r9 evidence: waves parked on
//     vmcnt; 16 vmem-instr per 8 outputs ~ TA issue ceiling; now 6)
//   - FIR + store pattern identical to r5/r7 (proven: WRITE 65.5MB exact,
//     conflict-free, absmax 0.0156): 6x ds_read_b128 window, 2x float4 store
//   - taps wave-uniform scalar loads; step==64 fast path rows (0,64)

#define QQ   128
#define LT   21
#define TT   4096
#define BLK  256

__global__ __launch_bounds__(BLK) void fir_kernel(
    const float* __restrict__ x,
    const float* __restrict__ hs,
    const float* __restrict__ accp,
    float*       __restrict__ y)
{
    __shared__ __align__(16) float xs[20 + TT];      // 16464 B
    const int tid = threadIdx.x;
    const size_t row = (size_t)blockIdx.x * TT;
    const float sf = 64.0f + accp[0];                // step_inc (f32)

    const float4* src = (const float4*)(x + row);    // row start 16B-aligned
    float4* dst = (float4*)(xs + 20);                // byte 80: 16B-aligned

    // ---- stage S0: x[0..2048) -> xs[20..2068), conflict-free b128 ----
    dst[tid]       = src[tid];
    dst[tid + 256] = src[tid + 256];
    if (tid < 20) xs[tid] = 0.0f;                    // FIFO zero-init head
    __syncthreads();

    // ---- issue S1 loads now; LDS-write them after compute-A ----
    float4 s1a = src[tid + 512];
    float4 s1b = src[tid + 768];

    const float4* xq = (const float4*)xs;            // quad g = xs floats [4g,4g+4)

    if (sf == 64.0f) {
        // a_t == 0 exactly for every t (2t integer) => rows (0,64) always.
        const float* __restrict__ h0 = hs;           // row 0
        const float* __restrict__ h1 = hs + 64 * LT; // row 64

        auto fir_it = [&](int it) {
            // window floats xs[t0 .. t0+24) = x[t0-20 .. t0+4), t0 = it*1024+4*tid
            const int qb = it * 256 + tid;           // byte 16*qb: stride-16B/lane
            float4 q0 = xq[qb+0], q1 = xq[qb+1], q2 = xq[qb+2],
                   q3 = xq[qb+3], q4 = xq[qb+4], q5 = xq[qb+5];
            float xr[24] = {q0.x,q0.y,q0.z,q0.w, q1.x,q1.y,q1.z,q1.w,
                            q2.x,q2.y,q2.z,q2.w, q3.x,q3.y,q3.z,q3.w,
                            q4.x,q4.y,q4.z,q4.w, q5.x,q5.y,q5.z,q5.w};
            float out[8];
            #pragma unroll
            for (int k = 0; k < 4; ++k) {
                float a0 = 0.0f, a1 = 0.0f;
                #pragma unroll
                for (int l = 0; l < LT; ++l) {
                    a0 = fmaf(h0[l], xr[k + l], a0);
                    a1 = fmaf(h1[l], xr[k + l], a1);
                }
                out[2*k] = a0; out[2*k+1] = a1;
            }
            const int t0 = it * 1024 + tid * 4;
            float4* yq = (float4*)(y + (row + (size_t)t0) * 2);
            yq[0] = make_float4(out[0], out[1], out[2], out[3]);
            yq[1] = make_float4(out[4], out[5], out[6], out[7]);
        };

        fir_it(0);
        fir_it(1);
        dst[tid + 512] = s1a;                        // S1 -> xs[2068..4116)
        dst[tid + 768] = s1b;
        __syncthreads();
        fir_it(2);
        fir_it(3);
        return;
    }

    // ---- generic acc_phase path (any step), same staging ----
    const double s = (double)sf;
    auto gen_it = [&](int it) {
        const int t0 = it * 1024 + tid * 4;
        const int qb = it * 256 + tid;
        float4 q0 = xq[qb+0], q1 = xq[qb+1], q2 = xq[qb+2],
               q3 = xq[qb+3], q4 = xq[qb+4], q5 = xq[qb+5];
        float xr[24] = {q0.x,q0.y,q0.z,q0.w, q1.x,q1.y,q1.z,q1.w,
                        q2.x,q2.y,q2.z,q2.w, q3.x,q3.y,q3.z,q3.w,
                        q4.x,q4.y,q4.z,q4.w, q5.x,q5.y,q5.z,q5.w};

        // f64 closed-form seed + exact reference f32 recurrence
        const double tq0 = (double)t0 * 128.0;
        float a = (float)(__builtin_ceil(tq0 / s) * s - tq0);
        int i0[4], i1[4];
        #pragma unroll
        for (int k = 0; k < 4; ++k) {
            bool  v0   = a < 128.0f;
            float ind0 = v0 ? a : -1.0f;
            float ap   = v0 ? a + sf : a;
            bool  v1   = ap < 128.0f;
            float ind1 = v1 ? ap : -1.0f;
            float an   = v1 ? ap + sf : ap;
            a = an - 128.0f;
            i0[k] = min((int)rintf(ind0), QQ - 1);   // -1 => NaN row
            i1[k] = min((int)rintf(ind1), QQ - 1);
        }
        bool uni = true;
        #pragma unroll
        for (int k = 1; k < 4; ++k) uni &= (i0[k] == i0[0]) & (i1[k] == i1[0]);
        const int f0 = __builtin_amdgcn_readfirstlane(i0[0]);
        const int f1 = __builtin_amdgcn_readfirstlane(i1[0]);
        uni &= (i0[0] == f0) & (i1[0] == f1);

        float out[8];
        if (__all(uni) && f0 >= 0 && f1 >= 0) {
            const float* __restrict__ h0 = hs + (size_t)f0 * LT;
            const float* __restrict__ h1 = hs + (size_t)f1 * LT;
            #pragma unroll
            for (int k = 0; k < 4; ++k) {
                float a0 = 0.0f, a1 = 0.0f;
                #pragma unroll
                for (int l = 0; l < LT; ++l) {
                    a0 = fmaf(h0[l], xr[k + l], a0);
                    a1 = fmaf(h1[l], xr[k + l], a1);
                }
                out[2*k] = a0; out[2*k+1] = a1;
            }
        } else {
            const float NaNf = __int_as_float(0x7fc00000);
            #pragma unroll
            for (int k = 0; k < 4; ++k) {
                const int r0 = i0[k], r1 = i1[k];
                float a0 = 0.0f, a1 = 0.0f;
                if (r0 >= 0) {
                    const float* hp = hs + (size_t)r0 * LT;
                    #pragma unroll
                    for (int l = 0; l < LT; ++l) a0 = fmaf(hp[l], xr[k + l], a0);
                } else a0 = NaNf;
                if (r1 >= 0) {
                    const float* hp = hs + (size_t)r1 * LT;
                    #pragma unroll
                    for (int l = 0; l < LT; ++l) a1 = fmaf(hp[l], xr[k + l], a1);
                } else a1 = NaNf;
                out[2*k] = a0; out[2*k+1] = a1;
            }
        }
        float4* yq = (float4*)(y + (row + (size_t)t0) * 2);
        yq[0] = make_float4(out[0], out[1], out[2], out[3]);
        yq[1] = make_float4(out[4], out[5], out[6], out[7]);
    };

    gen_it(0);
    gen_it(1);
    dst[tid + 512] = s1a;
    dst[tid + 768] = s1b;
    __syncthreads();
    gen_it(2);
    gen_it(3);
}

extern "C" void kernel_launch(void* const* d_in, const int* in_sizes, int n_in,
                              void* d_out, int out_size, void* d_ws, size_t ws_size,
                              hipStream_t stream) {
    const float* x    = (const float*)d_in[0];   // (B, 4096) f32
    const float* hs   = (const float*)d_in[1];   // (128, 21) f32
    const float* accp = (const float*)d_in[2];   // scalar f32
    float* y = (float*)d_out;                    // (B, 4096, 2) f32

    const int B = in_sizes[0] / TT;              // 2048 rows -> 8 blocks/CU

    fir_kernel<<<dim3(B), BLK, 0, stream>>>(x, hs, accp, y);
}

// Round 11
// 23.114 us; speedup vs baseline: 1.3605x; 1.0592x over previous
//
#include <hip/hip_runtime.h>
#include <cmath>

// VarRateResampler ratio=2: per (b,t) two 21-tap FIRs, polyphase rows chosen
// by an NCO with step s = 64 + acc_phase. Closed form for the NCO state
// entering step t:  a_t = ceil(t*Q/s)*s - t*Q  (invariant a in [0,Q)).
// FINAL = round-7 kernel, the empirical optimum (23.25us, reproduced twice).
// Structure: flat TPT=4, no LDS, no barrier, no prep kernel.
//  - x window (24 floats, 16B-aligned) via 6 global float4 loads
//  - NCO: exact a==0 shortcut for step==64, f64 closed form otherwise
//  - taps via wave-uniform scalar loads (s_load into SGPRs, once per wave)
//  - 2 regular float4 stores (WRITE_SIZE = 65.5 MB exact, no amplification)
// Measured ledger: NC=2 ILP 24.8 / TPT=8 31.4 / persistent+pipeline 25.4 /
// persistent+LDS 24.5 — every structural variant loses to this flat form.

#define QQ   128
#define LT   21
#define TT   4096
#define TPT  4                 // t per thread
#define BLK  256
#define TILE (BLK * TPT)       // 1024 t per block

__global__ __launch_bounds__(BLK) void fir_kernel(
    const float* __restrict__ x,
    const float* __restrict__ hs,
    const float* __restrict__ accp,
    float*       __restrict__ y)
{
    const int b  = blockIdx.y;
    const int t0 = blockIdx.x * TILE + threadIdx.x * TPT;
    const size_t row = (size_t)b * TT;

    // ---- x window x[t0-20 .. t0+3] : 24 floats, base (4m-20) is 16B-aligned ----
    float xr[24];
    const int base = t0 - 20;
    if (base >= 0) {
        const float4* src = (const float4*)(x + row + base);
        #pragma unroll
        for (int q = 0; q < 6; ++q) {
            float4 v = src[q];
            xr[4*q+0] = v.x; xr[4*q+1] = v.y; xr[4*q+2] = v.z; xr[4*q+3] = v.w;
        }
    } else {                        // only threads 0..4 of each row's first block
        #pragma unroll
        for (int i = 0; i < 24; ++i) {
            int gt = base + i;
            xr[i] = (gt >= 0) ? x[row + gt] : 0.0f;   // fifo zero-init
        }
    }

    // ---- NCO seed: exact shortcut for s==64, f64 closed form otherwise ----
    const float sf = 64.0f + accp[0];                 // step_inc (f32)
    float a;
    if (sf == 64.0f) {
        a = 0.0f;            // ceil(2t)=2t exactly => a_t = 0 for every t
    } else {
        const double s = (double)sf;
        const double tq0 = (double)t0 * 128.0;
        a = (float)(__builtin_ceil(tq0 / s) * s - tq0);   // acc entering t0
    }

    // ---- exact reference f32 recurrence over the 4 slots ----
    int i0[TPT], i1[TPT];
    #pragma unroll
    for (int k = 0; k < TPT; ++k) {
        bool  v0   = a < 128.0f;                      // slot 0
        float ind0 = v0 ? a : -1.0f;
        float ap   = v0 ? a + sf : a;
        bool  v1   = ap < 128.0f;                     // slot 1
        float ind1 = v1 ? ap : -1.0f;
        float an   = v1 ? ap + sf : ap;
        a = an - 128.0f;                              // wrap
        i0[k] = min((int)rintf(ind0), QQ - 1);        // -1 => NaN row
        i1[k] = min((int)rintf(ind1), QQ - 1);
    }

    // ---- wave-uniform fast path check ----
    bool uni = true;
    #pragma unroll
    for (int k = 1; k < TPT; ++k) uni &= (i0[k] == i0[0]) & (i1[k] == i1[0]);
    const int f0 = __builtin_amdgcn_readfirstlane(i0[0]);
    const int f1 = __builtin_amdgcn_readfirstlane(i1[0]);
    uni &= (i0[0] == f0) & (i1[0] == f1);

    float out[2 * TPT];

    if (__all(uni) && f0 >= 0 && f1 >= 0) {
        // taps are wave-uniform -> scalar loads into SGPRs, once per wave
        const float* __restrict__ h0 = hs + (size_t)f0 * LT;
        const float* __restrict__ h1 = hs + (size_t)f1 * LT;
        #pragma unroll
        for (int k = 0; k < TPT; ++k) {
            float a0 = 0.0f, a1 = 0.0f;
            #pragma unroll
            for (int l = 0; l < LT; ++l) {
                a0 = fmaf(h0[l], xr[k + l], a0);
                a1 = fmaf(h1[l], xr[k + l], a1);
            }
            out[2*k]     = a0;
            out[2*k + 1] = a1;
        }
    } else {
        // generic per-lane gather path (any acc_phase); correctness-only
        const float NaNf = __int_as_float(0x7fc00000);
        #pragma unroll
        for (int k = 0; k < TPT; ++k) {
            const int r0 = i0[k], r1 = i1[k];
            float a0 = 0.0f, a1 = 0.0f;
            if (r0 >= 0) {
                const float* hp = hs + (size_t)r0 * LT;
                #pragma unroll
                for (int l = 0; l < LT; ++l) a0 = fmaf(hp[l], xr[k + l], a0);
            } else a0 = NaNf;
            if (r1 >= 0) {
                const float* hp = hs + (size_t)r1 * LT;
                #pragma unroll
                for (int l = 0; l < LT; ++l) a1 = fmaf(hp[l], xr[k + l], a1);
            } else a1 = NaNf;
            out[2*k]     = a0;
            out[2*k + 1] = a1;
        }
    }

    // ---- write (B, T, 2): 8 floats = 2 REGULAR float4 stores, 32B stride ----
    float4* yq = (float4*)(y + (row + (size_t)t0) * 2);
    yq[0] = make_float4(out[0], out[1], out[2], out[3]);
    yq[1] = make_float4(out[4], out[5], out[6], out[7]);
}

extern "C" void kernel_launch(void* const* d_in, const int* in_sizes, int n_in,
                              void* d_out, int out_size, void* d_ws, size_t ws_size,
                              hipStream_t stream) {
    const float* x    = (const float*)d_in[0];   // (B, 4096) f32
    const float* hs   = (const float*)d_in[1];   // (128, 21) f32
    const float* accp = (const float*)d_in[2];   // scalar f32
    float* y = (float*)d_out;                    // (B, 4096, 2) f32

    const int B = in_sizes[0] / TT;

    dim3 grid(TT / TILE, B);                     // (4, 2048)
    fir_kernel<<<grid, BLK, 0, stream>>>(x, hs, accp, y);
}